// Round 17
// baseline (418.920 us; speedup 1.0000x reference)
//
#include <hip/hip_runtime.h>
#include <hip/hip_bf16.h>
#include <math.h>

#define N_TOK 8192
#define D_IN  1024
#define D_QK  128

typedef short bf16x8 __attribute__((ext_vector_type(8)));
typedef float f32x4 __attribute__((ext_vector_type(4)));
typedef unsigned short u16;
typedef u16 u16x8 __attribute__((ext_vector_type(8)));

static __device__ __forceinline__ u16 f2bf(float f) {
  __hip_bfloat16 b = __float2bfloat16(f);
  return *(u16*)&b;
}
static __device__ __forceinline__ float bf2f(u16 u) {
  __hip_bfloat16 b = *(__hip_bfloat16*)&u;
  return __bfloat162float(b);
}

static __device__ __forceinline__ void gload_lds16(const void* g, void* lds) {
  __builtin_amdgcn_global_load_lds(
      (const __attribute__((address_space(1))) unsigned int*)g,
      (__attribute__((address_space(3))) unsigned int*)lds, 16, 0, 0);
}

// ---------------------------------------------------------------------------
// bf16 MFMA GEMM: C[M][N] = A[M][K] * B[N][K]^T, 128x128 tile, BK=32.
// OUT_MODE: 0 = bf16 row-major, 1 = f32 row-major, 2 = bf16 frag-tiled vtt.
// ---------------------------------------------------------------------------
template <int OUT_MODE>
__global__ __launch_bounds__(256, 2) void gemm_mfma(const u16* __restrict__ A,
                                                    const u16* __restrict__ B,
                                                    void* __restrict__ Cv,
                                                    int M, int N, int K) {
  __shared__ __align__(16) u16 As[128 * 32];
  __shared__ __align__(16) u16 Bs[128 * 32];
  const int tid = threadIdx.x;
  const int w = tid >> 6, l = tid & 63;
  const int lr = l & 15, lg = l >> 4;
  const int m0 = blockIdx.y * 128, n0 = blockIdx.x * 128;
  const int wr = (w >> 1) * 64, wc = (w & 1) * 64;

  f32x4 acc[4][4];
#pragma unroll
  for (int m = 0; m < 4; ++m)
#pragma unroll
    for (int n = 0; n < 4; ++n) {
      f32x4 z = {0.f, 0.f, 0.f, 0.f};
      acc[m][n] = z;
    }

  const int ldsb0 = (w * 2 + 0) * 1024;
  const int ldsb1 = (w * 2 + 1) * 1024;
  const int srow0 = (w * 2 + 0) * 16 + (l >> 2);
  const int srow1 = (w * 2 + 1) * 16 + (l >> 2);
  const int scol = (l & 3) * 8;

  for (int kt = 0; kt < K; kt += 32) {
    gload_lds16(A + (size_t)(m0 + srow0) * K + kt + scol, (char*)As + ldsb0);
    gload_lds16(A + (size_t)(m0 + srow1) * K + kt + scol, (char*)As + ldsb1);
    gload_lds16(B + (size_t)(n0 + srow0) * K + kt + scol, (char*)Bs + ldsb0);
    gload_lds16(B + (size_t)(n0 + srow1) * K + kt + scol, (char*)Bs + ldsb1);
    __syncthreads();
    bf16x8 af[4], bfr[4];
#pragma unroll
    for (int m = 0; m < 4; ++m)
      af[m] = *(const bf16x8*)((char*)As + (wr + m * 16 + lr) * 64 + lg * 16);
#pragma unroll
    for (int n = 0; n < 4; ++n)
      bfr[n] = *(const bf16x8*)((char*)Bs + (wc + n * 16 + lr) * 64 + lg * 16);
#pragma unroll
    for (int m = 0; m < 4; ++m)
#pragma unroll
      for (int n = 0; n < 4; ++n)
        acc[m][n] = __builtin_amdgcn_mfma_f32_16x16x32_bf16(af[m], bfr[n], acc[m][n], 0, 0, 0);
    __syncthreads();
  }
#pragma unroll
  for (int m = 0; m < 4; ++m)
#pragma unroll
    for (int n = 0; n < 4; ++n)
#pragma unroll
      for (int r = 0; r < 4; ++r) {
        const int row = m0 + wr + m * 16 + lg * 4 + r;
        const int col = n0 + wc + n * 16 + lr;
        if (OUT_MODE == 1) {
          ((float*)Cv)[(size_t)row * N + col] = acc[m][n][r];
        } else if (OUT_MODE == 0) {
          ((u16*)Cv)[(size_t)row * N + col] = f2bf(acc[m][n][r]);
        } else {  // fragment-tiled vtt
          const size_t adr = ((size_t)(row >> 4) * 256 + (col >> 5)) * 512 +
                             ((row & 15) + (((col >> 3) & 3) << 4)) * 8 + (col & 7);
          ((u16*)Cv)[adr] = f2bf(acc[m][n][r]);
        }
      }
}

// ---------------------------------------------------------------------------
// hi/lo 3-term MFMA GEMM for q,k (f32-equivalent accuracy).
// ---------------------------------------------------------------------------
__global__ __launch_bounds__(256, 2) void gemm_hilo(
    const u16* __restrict__ Ah, const u16* __restrict__ Al,
    const u16* __restrict__ BhQ, const u16* __restrict__ BlQ,
    u16* __restrict__ ChQ, u16* __restrict__ ClQ,
    const u16* __restrict__ BhK, const u16* __restrict__ BlK,
    u16* __restrict__ ChK, u16* __restrict__ ClK, int K) {
  const bool isQ = (blockIdx.x == 0);
  const u16* Bh = isQ ? BhQ : BhK;
  const u16* Bl = isQ ? BlQ : BlK;
  u16* Ch = isQ ? ChQ : ChK;
  u16* Cl = isQ ? ClQ : ClK;
  const float scale = isQ ? 11.31370849898476f : 1.0f;
  __shared__ __align__(16) u16 Ahs[64 * 32], Als[64 * 32];
  __shared__ __align__(16) u16 Bhs[128 * 32], Bls[128 * 32];
  const int tid = threadIdx.x;
  const int w = tid >> 6, l = tid & 63;
  const int lr = l & 15, lg = l >> 4;
  const int m0 = blockIdx.y * 64;
  const int wc = w * 32;

  f32x4 acc[4][2];
#pragma unroll
  for (int m = 0; m < 4; ++m)
#pragma unroll
    for (int n = 0; n < 2; ++n) {
      f32x4 z = {0.f, 0.f, 0.f, 0.f};
      acc[m][n] = z;
    }

  const int arow = w * 16 + (l >> 2);
  const int brow0 = (w * 2 + 0) * 16 + (l >> 2);
  const int brow1 = (w * 2 + 1) * 16 + (l >> 2);
  const int scol = (l & 3) * 8;

  for (int kt = 0; kt < K; kt += 32) {
    gload_lds16(Ah + (size_t)(m0 + arow) * K + kt + scol, (char*)Ahs + w * 1024);
    gload_lds16(Al + (size_t)(m0 + arow) * K + kt + scol, (char*)Als + w * 1024);
    gload_lds16(Bh + (size_t)brow0 * K + kt + scol, (char*)Bhs + (w * 2 + 0) * 1024);
    gload_lds16(Bh + (size_t)brow1 * K + kt + scol, (char*)Bhs + (w * 2 + 1) * 1024);
    gload_lds16(Bl + (size_t)brow0 * K + kt + scol, (char*)Bls + (w * 2 + 0) * 1024);
    gload_lds16(Bl + (size_t)brow1 * K + kt + scol, (char*)Bls + (w * 2 + 1) * 1024);
    __syncthreads();
    bf16x8 afh[4], afl[4], bfh[2], bfl[2];
#pragma unroll
    for (int m = 0; m < 4; ++m) {
      afh[m] = *(const bf16x8*)((char*)Ahs + (m * 16 + lr) * 64 + lg * 16);
      afl[m] = *(const bf16x8*)((char*)Als + (m * 16 + lr) * 64 + lg * 16);
    }
#pragma unroll
    for (int n = 0; n < 2; ++n) {
      bfh[n] = *(const bf16x8*)((char*)Bhs + (wc + n * 16 + lr) * 64 + lg * 16);
      bfl[n] = *(const bf16x8*)((char*)Bls + (wc + n * 16 + lr) * 64 + lg * 16);
    }
#pragma unroll
    for (int m = 0; m < 4; ++m)
#pragma unroll
      for (int n = 0; n < 2; ++n) {
        acc[m][n] = __builtin_amdgcn_mfma_f32_16x16x32_bf16(afh[m], bfh[n], acc[m][n], 0, 0, 0);
        acc[m][n] = __builtin_amdgcn_mfma_f32_16x16x32_bf16(afh[m], bfl[n], acc[m][n], 0, 0, 0);
        acc[m][n] = __builtin_amdgcn_mfma_f32_16x16x32_bf16(afl[m], bfh[n], acc[m][n], 0, 0, 0);
      }
    __syncthreads();
  }
#pragma unroll
  for (int m = 0; m < 4; ++m)
#pragma unroll
    for (int n = 0; n < 2; ++n)
#pragma unroll
      for (int r = 0; r < 4; ++r) {
        const size_t row = m0 + m * 16 + lg * 4 + r;
        const size_t col = wc + n * 16 + lr;
        const float v = acc[m][n][r] * scale;
        const u16 h = f2bf(v);
        Ch[row * 128 + col] = h;
        Cl[row * 128 + col] = f2bf(v - bf2f(h));
      }
}

// ---------------------------------------------------------------------------
__global__ __launch_bounds__(256) void cvt_bf16(const float* __restrict__ in,
                                                u16* __restrict__ out) {
  const size_t idx = (size_t)blockIdx.x * 256 + threadIdx.x;
  const float4 a = ((const float4*)in)[idx * 2];
  const float4 b = ((const float4*)in)[idx * 2 + 1];
  u16x8 o;
  o[0] = f2bf(a.x); o[1] = f2bf(a.y); o[2] = f2bf(a.z); o[3] = f2bf(a.w);
  o[4] = f2bf(b.x); o[5] = f2bf(b.y); o[6] = f2bf(b.z); o[7] = f2bf(b.w);
  ((u16x8*)out)[idx] = o;
}

__global__ __launch_bounds__(256) void split_hl(const float* __restrict__ in,
                                                u16* __restrict__ hi,
                                                u16* __restrict__ lo) {
  const size_t idx = (size_t)blockIdx.x * 256 + threadIdx.x;
  const float4 v = ((const float4*)in)[idx];
  float f[4] = {v.x, v.y, v.z, v.w};
  u16 h[4], g[4];
#pragma unroll
  for (int i = 0; i < 4; ++i) {
    h[i] = f2bf(f[i]);
    g[i] = f2bf(f[i] - bf2f(h[i]));
  }
  ushort4 hv; hv.x = h[0]; hv.y = h[1]; hv.z = h[2]; hv.w = h[3];
  ushort4 gv; gv.x = g[0]; gv.y = g[1]; gv.z = g[2]; gv.w = g[3];
  ((ushort4*)hi)[idx] = hv;
  ((ushort4*)lo)[idx] = gv;
}

// ---------------------------------------------------------------------------
// repack k hi/lo row-major [8192][128] -> MFMA-fragment-tiled (1 KB frags).
// ---------------------------------------------------------------------------
__global__ __launch_bounds__(256) void repack_k(const u16* __restrict__ krh,
                                                const u16* __restrict__ krl,
                                                u16* __restrict__ khT,
                                                u16* __restrict__ klT) {
  const int gid = blockIdx.x * 256 + threadIdx.x;
  const int f = gid >> 6, l = gid & 63;
  const int fn = f >> 2, fk = f & 3;
  const size_t src = (size_t)(fn * 16 + (l & 15)) * 128 + fk * 32 + (l >> 4) * 8;
  *(u16x8*)(khT + (size_t)f * 512 + l * 8) = *(const u16x8*)(krh + src);
  *(u16x8*)(klT + (size_t)f * 512 + l * 8) = *(const u16x8*)(krl + src);
}

// ---------------------------------------------------------------------------
// MFMA flash attention, KV-split (flash-decoding): grid (2 v-halves, 128 qb,
// 2 kv-halves) = 512 blocks x 8 waves. Each block: 32 of the 64 KV tiles.
// Emits UNNORMALIZED O-partials (bf16, contiguous 32 MB: z-half stride
// N_TOK*D_IN) + per-row m,l; combined downstream.
// ---------------------------------------------------------------------------
__global__ __launch_bounds__(512) __attribute__((amdgpu_waves_per_eu(2, 4)))
void flash_attn_mfma(const u16* __restrict__ qh, const u16* __restrict__ ql,
                     const u16* __restrict__ khT, const u16* __restrict__ klT,
                     const u16* __restrict__ vt, u16* __restrict__ part,
                     float* __restrict__ mfin, float* __restrict__ lfin) {
  __shared__ __align__(16) u16 Qs[2 * 8192];   // hi|lo, 64x128 swizzled (32 KB)
  __shared__ __align__(16) u16 P[64 * 128];    // 16 KB swizzled
  __shared__ __align__(16) float pmax[64][12];
  __shared__ __align__(16) float lpart[64][12];
  __shared__ __align__(16) float facl[64];
  const int tid = threadIdx.x;
  const int w = tid >> 6, l = tid & 63;
  const int lr = l & 15, lg = l >> 4;
  const int q0 = blockIdx.y * 64;
  const int half = blockIdx.x;
  const int z = blockIdx.z;       // kv-half
  const int tbase = z * 32;

  {  // stage Q hi/lo into swizzled LDS
#pragma unroll
    for (int i = 0; i < 2; ++i) {
      const int e = i * 512 + tid;  // 0..1023
      const int row = e >> 4, c16 = e & 15;
      const u16x8 hv = *(const u16x8*)(qh + (size_t)(q0 + row) * 128 + c16 * 8);
      const u16x8 lv = *(const u16x8*)(ql + (size_t)(q0 + row) * 128 + c16 * 8);
      const int b = (row * 256 + c16 * 16) ^ ((row & 7) << 4);
      *(u16x8*)((char*)Qs + b) = hv;
      *(u16x8*)((char*)Qs + 16384 + b) = lv;
    }
  }

  float mrun4[4] = {-INFINITY, -INFINITY, -INFINITY, -INFINITY};
  float lrun4[4] = {0.f, 0.f, 0.f, 0.f};

  f32x4 acc[4][4];
#pragma unroll
  for (int mt = 0; mt < 4; ++mt)
#pragma unroll
    for (int nt = 0; nt < 4; ++nt) {
      f32x4 z4 = {0.f, 0.f, 0.f, 0.f};
      acc[mt][nt] = z4;
    }

  bf16x8 kfh[4], kfl[4];
#pragma unroll
  for (int ks = 0; ks < 4; ++ks) {
    kfh[ks] = *(const bf16x8*)(khT + ((size_t)(tbase * 8 + w) * 4 + ks) * 512 + l * 8);
    kfl[ks] = *(const bf16x8*)(klT + ((size_t)(tbase * 8 + w) * 4 + ks) * 512 + l * 8);
  }
  __syncthreads();

  const int vcol0 = half * 32 + w * 4;

  for (int tt = 0; tt < 32; ++tt) {
    const int t = tbase + tt;
    const int c = t * 4;
    // ---- scores (swapped): sfT[mt][r] = S^T[k][q] ----
    f32x4 sfT[4];
#pragma unroll
    for (int mt = 0; mt < 4; ++mt) {
      f32x4 z4 = {0.f, 0.f, 0.f, 0.f};
      sfT[mt] = z4;
    }
    __builtin_amdgcn_s_setprio(1);
#pragma unroll
    for (int ks = 0; ks < 4; ++ks)
#pragma unroll
      for (int mt = 0; mt < 4; ++mt) {
        const int b = ((mt * 16 + lr) * 256 + ks * 64 + lg * 16) ^ ((lr & 7) << 4);
        const bf16x8 qfh = *(const bf16x8*)((char*)Qs + b);
        const bf16x8 qfl = *(const bf16x8*)((char*)Qs + 16384 + b);
        sfT[mt] = __builtin_amdgcn_mfma_f32_16x16x32_bf16(kfh[ks], qfh, sfT[mt], 0, 0, 0);
        sfT[mt] = __builtin_amdgcn_mfma_f32_16x16x32_bf16(kfl[ks], qfh, sfT[mt], 0, 0, 0);
        sfT[mt] = __builtin_amdgcn_mfma_f32_16x16x32_bf16(kfh[ks], qfl, sfT[mt], 0, 0, 0);
      }
    __builtin_amdgcn_s_setprio(0);
    // ---- early issue: K(t+1) + V(ks0) (land during softmax) ----
    if (tt < 31) {
#pragma unroll
      for (int ks = 0; ks < 4; ++ks) {
        kfh[ks] = *(const bf16x8*)(khT + ((size_t)((t + 1) * 8 + w) * 4 + ks) * 512 + l * 8);
        kfl[ks] = *(const bf16x8*)(klT + ((size_t)((t + 1) * 8 + w) * 4 + ks) * 512 + l * 8);
      }
    }
    bf16x8 vA[4], vB[4];
#pragma unroll
    for (int nt = 0; nt < 4; ++nt)
      vA[nt] = *(const bf16x8*)(vt + ((size_t)(vcol0 + nt) * 256 + c + 0) * 512 + l * 8);

    // ---- wave-slice max ----
    float wmax[4];
#pragma unroll
    for (int mt = 0; mt < 4; ++mt)
      wmax[mt] = fmaxf(fmaxf(sfT[mt][0], sfT[mt][1]), fmaxf(sfT[mt][2], sfT[mt][3]));
#pragma unroll
    for (int mt = 0; mt < 4; ++mt) {
      wmax[mt] = fmaxf(wmax[mt], __shfl_xor(wmax[mt], 16));
      wmax[mt] = fmaxf(wmax[mt], __shfl_xor(wmax[mt], 32));
    }
    if (lg == 0) {
#pragma unroll
      for (int mt = 0; mt < 4; ++mt) pmax[mt * 16 + lr][w] = wmax[mt];
    }
    __syncthreads();  // BAR1

    // ---- global max, fac, exp, pack P, wave-partial sum ----
    float mn4[4], fac4[4];
#pragma unroll
    for (int mt = 0; mt < 4; ++mt) {
      const int q = mt * 16 + lr;
      const f32x4 a = *(const f32x4*)&pmax[q][0];
      const f32x4 b = *(const f32x4*)&pmax[q][4];
      const float mx = fmaxf(fmaxf(fmaxf(a[0], a[1]), fmaxf(a[2], a[3])),
                             fmaxf(fmaxf(b[0], b[1]), fmaxf(b[2], b[3])));
      const float mn = fmaxf(mrun4[mt], mx);
      fac4[mt] = __expf(mrun4[mt] - mn);
      mn4[mt] = mn;
      mrun4[mt] = mn;
    }
    if (w == 0 && lg == 0) {
#pragma unroll
      for (int mt = 0; mt < 4; ++mt) facl[mt * 16 + lr] = fac4[mt];
    }
#pragma unroll
    for (int mt = 0; mt < 4; ++mt) {
      const float e0 = __expf(sfT[mt][0] - mn4[mt]);
      const float e1 = __expf(sfT[mt][1] - mn4[mt]);
      const float e2 = __expf(sfT[mt][2] - mn4[mt]);
      const float e3 = __expf(sfT[mt][3] - mn4[mt]);
      float tot = (e0 + e1) + (e2 + e3);
      tot += __shfl_xor(tot, 16);
      tot += __shfl_xor(tot, 32);
      lrun4[mt] = lrun4[mt] * fac4[mt] + tot;
      ushort4 pb;
      pb.x = f2bf(e0); pb.y = f2bf(e1); pb.z = f2bf(e2); pb.w = f2bf(e3);
      const int q = mt * 16 + lr;
      const int byte = (q * 256 + w * 32 + lg * 8) ^ ((q & 7) << 4);
      *(ushort4*)((char*)P + byte) = pb;
    }
    __syncthreads();  // BAR2

    // ---- rescale accumulators ----
#pragma unroll
    for (int mt = 0; mt < 4; ++mt) {
      const f32x4 f4 = *(const f32x4*)&facl[mt * 16 + lg * 4];
#pragma unroll
      for (int rr = 0; rr < 4; ++rr) {
        const float f = f4[rr];
        if (f != 1.0f) {
#pragma unroll
          for (int nt = 0; nt < 4; ++nt) acc[mt][nt][rr] *= f;
        }
      }
    }

    // ---- PV: 2-deep register ping-pong over ks ----
#pragma unroll
    for (int ks = 0; ks < 4; ++ks) {
      bf16x8* nxt = (ks & 1) ? vA : vB;
      if (ks < 3) {
#pragma unroll
        for (int nt = 0; nt < 4; ++nt)
          nxt[nt] = *(const bf16x8*)(vt + ((size_t)(vcol0 + nt) * 256 + c + ks + 1) * 512 + l * 8);
      }
      const bf16x8* cur = (ks & 1) ? vB : vA;
      bf16x8 pf[4];
#pragma unroll
      for (int mt = 0; mt < 4; ++mt) {
        const int row = mt * 16 + lr;
        pf[mt] = *(const bf16x8*)((char*)P + ((row * 256 + ks * 64 + lg * 16) ^ ((row & 7) << 4)));
      }
      __builtin_amdgcn_s_setprio(1);
#pragma unroll
      for (int mt = 0; mt < 4; ++mt)
#pragma unroll
        for (int nt = 0; nt < 4; ++nt)
          acc[mt][nt] = __builtin_amdgcn_mfma_f32_16x16x32_bf16(pf[mt], cur[nt], acc[mt][nt], 0, 0, 0);
      __builtin_amdgcn_s_setprio(0);
    }
  }
  // ---- epilogue: write unnormalized partials (bf16) + m,l ----
  if (lg == 0) {
#pragma unroll
    for (int mt = 0; mt < 4; ++mt) lpart[mt * 16 + lr][w] = lrun4[mt];
  }
  if (w == 0 && lg == 0) {
#pragma unroll
    for (int mt = 0; mt < 4; ++mt)
      mfin[(size_t)z * N_TOK + q0 + mt * 16 + lr] = mrun4[mt];
  }
  __syncthreads();
  u16* pz = part + (size_t)z * N_TOK * D_IN;
#pragma unroll
  for (int mt = 0; mt < 4; ++mt)
#pragma unroll
    for (int rr = 0; rr < 4; ++rr) {
      const int row = mt * 16 + lg * 4 + rr;
      const f32x4 a = *(const f32x4*)&lpart[row][0];
      const f32x4 b = *(const f32x4*)&lpart[row][4];
      const float lsum =
          ((a[0] + a[1]) + (a[2] + a[3])) + ((b[0] + b[1]) + (b[2] + b[3]));
      if (w == 0 && lr == 0) lfin[(size_t)z * N_TOK + q0 + row] = lsum;
#pragma unroll
      for (int nt = 0; nt < 4; ++nt)
        pz[(size_t)(q0 + row) * 1024 + half * 512 + w * 64 + nt * 16 + lr] =
            f2bf(acc[mt][nt][rr]);
    }
}

// ---------------------------------------------------------------------------
// Combine kv-half partials + residual + LayerNorm (fused):
// sa = (e^{m0-m} O~0 + e^{m1-m} O~1) / (e^{m0-m} l0 + e^{m1-m} l1)
// writes sa (bf16, for the final LN) and h = LN(x + sa) (bf16).
// ---------------------------------------------------------------------------
__global__ __launch_bounds__(256) void comb_ln(const u16* __restrict__ part,
                                               const float* __restrict__ mfin,
                                               const float* __restrict__ lfin,
                                               const float* __restrict__ x,
                                               u16* __restrict__ sa_bf,
                                               u16* __restrict__ hb) {
  const int row = blockIdx.x;
  const int tid = threadIdx.x;
  const size_t base = (size_t)row * 256 + tid;
  const float m0 = mfin[row], m1 = mfin[N_TOK + row];
  const float l0 = lfin[row], l1 = lfin[N_TOK + row];
  const float m = fmaxf(m0, m1);
  const float a0 = __expf(m0 - m), a1 = __expf(m1 - m);
  const float inv = 1.0f / (a0 * l0 + a1 * l1);
  const float s0 = a0 * inv, s1 = a1 * inv;
  const ushort4 p0 = ((const ushort4*)part)[base];
  const ushort4 p1 = ((const ushort4*)(part + (size_t)N_TOK * D_IN))[base];
  float o0 = s0 * bf2f(p0.x) + s1 * bf2f(p1.x);
  float o1 = s0 * bf2f(p0.y) + s1 * bf2f(p1.y);
  float o2 = s0 * bf2f(p0.z) + s1 * bf2f(p1.z);
  float o3 = s0 * bf2f(p0.w) + s1 * bf2f(p1.w);
  ushort4 sv;
  sv.x = f2bf(o0); sv.y = f2bf(o1); sv.z = f2bf(o2); sv.w = f2bf(o3);
  ((ushort4*)sa_bf)[base] = sv;
  const float4 xv = ((const float4*)x)[base];
  float4 y;
  y.x = xv.x + o0; y.y = xv.y + o1; y.z = xv.z + o2; y.w = xv.w + o3;
  float s1r = y.x + y.y + y.z + y.w;
  float s2r = y.x * y.x + y.y * y.y + y.z * y.z + y.w * y.w;
#pragma unroll
  for (int off = 32; off > 0; off >>= 1) {
    s1r += __shfl_xor(s1r, off);
    s2r += __shfl_xor(s2r, off);
  }
  __shared__ float r1[4];
  __shared__ float r2[4];
  if ((tid & 63) == 0) { r1[tid >> 6] = s1r; r2[tid >> 6] = s2r; }
  __syncthreads();
  s1r = r1[0] + r1[1] + r1[2] + r1[3];
  s2r = r2[0] + r2[1] + r2[2] + r2[3];
  const float mu = s1r * (1.0f / 1024.0f);
  const float var = s2r * (1.0f / 1024.0f) - mu * mu;
  const float rs = rsqrtf(var + 1e-5f);
  ushort4 ov;
  ov.x = f2bf((y.x - mu) * rs); ov.y = f2bf((y.y - mu) * rs);
  ov.z = f2bf((y.z - mu) * rs); ov.w = f2bf((y.w - mu) * rs);
  ((ushort4*)hb)[base] = ov;
}

// ---------------------------------------------------------------------------
// out(f32) = LayerNorm(sa_bf16 + out) over last dim 1024, in place.
// ---------------------------------------------------------------------------
__global__ __launch_bounds__(256) void ln_final(const u16* __restrict__ sa_bf,
                                                float* __restrict__ o) {
  const int row = blockIdx.x;
  const int tid = threadIdx.x;
  const size_t base = (size_t)row * 256 + tid;
  const ushort4 sv = ((const ushort4*)sa_bf)[base];
  const float4 ov = ((const float4*)o)[base];
  float4 y;
  y.x = ov.x + bf2f(sv.x); y.y = ov.y + bf2f(sv.y);
  y.z = ov.z + bf2f(sv.z); y.w = ov.w + bf2f(sv.w);
  float s1 = y.x + y.y + y.z + y.w;
  float s2 = y.x * y.x + y.y * y.y + y.z * y.z + y.w * y.w;
#pragma unroll
  for (int off = 32; off > 0; off >>= 1) {
    s1 += __shfl_xor(s1, off);
    s2 += __shfl_xor(s2, off);
  }
  __shared__ float r1[4];
  __shared__ float r2[4];
  if ((tid & 63) == 0) { r1[tid >> 6] = s1; r2[tid >> 6] = s2; }
  __syncthreads();
  s1 = r1[0] + r1[1] + r1[2] + r1[3];
  s2 = r2[0] + r2[1] + r2[2] + r2[3];
  const float mu = s1 * (1.0f / 1024.0f);
  const float var = s2 * (1.0f / 1024.0f) - mu * mu;
  const float rs = rsqrtf(var + 1e-5f);
  float4 res;
  res.x = (y.x - mu) * rs; res.y = (y.y - mu) * rs;
  res.z = (y.z - mu) * rs; res.w = (y.w - mu) * rs;
  ((float4*)o)[base] = res;
}

// ---------------------------------------------------------------------------
extern "C" void kernel_launch(void* const* d_in, const int* in_sizes, int n_in,
                              void* d_out, int out_size, void* d_ws, size_t ws_size,
                              hipStream_t stream) {
  const float* x  = (const float*)d_in[0];
  const float* Wq = (const float*)d_in[1];
  const float* Wk = (const float*)d_in[2];
  const float* Wv = (const float*)d_in[3];
  const float* Wl = (const float*)d_in[4];
  float* out = (float*)d_out;

  // workspace layout (<=100 MB), lifetime-aliased:
  //  0-16 : xh (dead after gemm_hilo)   -> sa_bf (written by comb_ln)
  // 16-20 : xl head -> khT(16-18), klT(18-20)  [LIVE during flash]
  // 20-36 : xl tail -> hb@20 (written by comb_ln); qh@32, ql@34 [live in flash]
  // 36-40 : krh/krl -> mfin/lfin after repack_k
  // 48-64 : vtt [live during flash]
  // 64-96 : part (contiguous 32 MB: z0 at 64-80, z1 at 80-96)
  // 92-93 : wq/wk splits (consumed by gemm_hilo BEFORE flash writes part!)
  //         -> moved to 40-44 to avoid overlap with part.
  // 96-100: Wvb, Wlb [live until final GEMM]
  char* w8 = (char*)d_ws;
  u16* xh    = (u16*)(w8 + (0ull << 20));
  u16* xl    = (u16*)(w8 + (16ull << 20));
  u16* khT   = (u16*)(w8 + (16ull << 20));
  u16* klT   = (u16*)(w8 + (18ull << 20));
  u16* sa_bf = (u16*)(w8 + (0ull << 20));
  u16* hb    = (u16*)(w8 + (20ull << 20));
  u16* qh    = (u16*)(w8 + (32ull << 20));
  u16* ql    = (u16*)(w8 + (34ull << 20));
  u16* krh   = (u16*)(w8 + (36ull << 20));
  u16* krl   = (u16*)(w8 + (38ull << 20));
  float* mfin = (float*)(w8 + (36ull << 20));
  float* lfin = (float*)(w8 + (36ull << 20) + (128ull << 10));
  u16* wqh = (u16*)(w8 + (40ull << 20));
  u16* wql = (u16*)(w8 + (40ull << 20) + (256ull << 10));
  u16* wkh = (u16*)(w8 + (40ull << 20) + (512ull << 10));
  u16* wkl = (u16*)(w8 + (40ull << 20) + (768ull << 10));
  u16* vtt   = (u16*)(w8 + (48ull << 20));
  u16* part  = (u16*)(w8 + (64ull << 20));  // contiguous 32 MB
  u16* Wvb = (u16*)(w8 + (96ull << 20));
  u16* Wlb = (u16*)(w8 + (98ull << 20));

  split_hl<<<8192, 256, 0, stream>>>(x, xh, xl);
  cvt_bf16<<<512, 256, 0, stream>>>(Wv, Wvb);
  cvt_bf16<<<512, 256, 0, stream>>>(Wl, Wlb);
  // v-GEMM writes the fragment-tiled vtt directly (mode 2).
  gemm_mfma<2><<<dim3(64, 8), 256, 0, stream>>>(Wvb, xh, (void*)vtt, D_IN, N_TOK, D_IN);
  split_hl<<<128, 256, 0, stream>>>(Wq, wqh, wql);
  split_hl<<<128, 256, 0, stream>>>(Wk, wkh, wkl);
  gemm_hilo<<<dim3(2, 128), 256, 0, stream>>>(xh, xl, wqh, wql, qh, ql,
                                              wkh, wkl, krh, krl, D_IN);
  repack_k<<<512, 256, 0, stream>>>(krh, krl, khT, klT);
  // KV-split flash: 512 blocks, unnormalized partials per kv-half.
  flash_attn_mfma<<<dim3(2, 128, 2), 512, 0, stream>>>(qh, ql, khT, klT, vtt,
                                                       part, mfin, lfin);
  // combine + residual + LN1 (fused); emits sa (bf16) and h (bf16).
  comb_ln<<<N_TOK, 256, 0, stream>>>(part, mfin, lfin, x, sa_bf, hb);
  gemm_mfma<1><<<dim3(8, 64), 256, 0, stream>>>(hb, Wlb, (void*)out, N_TOK, D_IN, D_IN);
  ln_final<<<N_TOK, 256, 0, stream>>>(sa_bf, out);
}

// Round 18
// 418.860 us; speedup vs baseline: 1.0001x; 1.0001x over previous
//
#include <hip/hip_runtime.h>
#include <hip/hip_bf16.h>
#include <math.h>

#define N_TOK 8192
#define D_IN  1024
#define D_QK  128

typedef short bf16x8 __attribute__((ext_vector_type(8)));
typedef float f32x4 __attribute__((ext_vector_type(4)));
typedef unsigned short u16;
typedef u16 u16x8 __attribute__((ext_vector_type(8)));

static __device__ __forceinline__ u16 f2bf(float f) {
  __hip_bfloat16 b = __float2bfloat16(f);
  return *(u16*)&b;
}
static __device__ __forceinline__ float bf2f(u16 u) {
  __hip_bfloat16 b = *(__hip_bfloat16*)&u;
  return __bfloat162float(b);
}

static __device__ __forceinline__ void gload_lds16(const void* g, void* lds) {
  __builtin_amdgcn_global_load_lds(
      (const __attribute__((address_space(1))) unsigned int*)g,
      (__attribute__((address_space(3))) unsigned int*)lds, 16, 0, 0);
}

// ---------------------------------------------------------------------------
// bf16 MFMA GEMM: C[M][N] = A[M][K] * B[N][K]^T, 128x128 tile, BK=32.
// OUT_MODE: 0 = bf16 row-major, 1 = f32 row-major, 2 = bf16 frag-tiled vtt.
// ---------------------------------------------------------------------------
template <int OUT_MODE>
__global__ __launch_bounds__(256, 2) void gemm_mfma(const u16* __restrict__ A,
                                                    const u16* __restrict__ B,
                                                    void* __restrict__ Cv,
                                                    int M, int N, int K) {
  __shared__ __align__(16) u16 As[128 * 32];
  __shared__ __align__(16) u16 Bs[128 * 32];
  const int tid = threadIdx.x;
  const int w = tid >> 6, l = tid & 63;
  const int lr = l & 15, lg = l >> 4;
  const int m0 = blockIdx.y * 128, n0 = blockIdx.x * 128;
  const int wr = (w >> 1) * 64, wc = (w & 1) * 64;

  f32x4 acc[4][4];
#pragma unroll
  for (int m = 0; m < 4; ++m)
#pragma unroll
    for (int n = 0; n < 4; ++n) {
      f32x4 z = {0.f, 0.f, 0.f, 0.f};
      acc[m][n] = z;
    }

  const int ldsb0 = (w * 2 + 0) * 1024;
  const int ldsb1 = (w * 2 + 1) * 1024;
  const int srow0 = (w * 2 + 0) * 16 + (l >> 2);
  const int srow1 = (w * 2 + 1) * 16 + (l >> 2);
  const int scol = (l & 3) * 8;

  for (int kt = 0; kt < K; kt += 32) {
    gload_lds16(A + (size_t)(m0 + srow0) * K + kt + scol, (char*)As + ldsb0);
    gload_lds16(A + (size_t)(m0 + srow1) * K + kt + scol, (char*)As + ldsb1);
    gload_lds16(B + (size_t)(n0 + srow0) * K + kt + scol, (char*)Bs + ldsb0);
    gload_lds16(B + (size_t)(n0 + srow1) * K + kt + scol, (char*)Bs + ldsb1);
    __syncthreads();
    bf16x8 af[4], bfr[4];
#pragma unroll
    for (int m = 0; m < 4; ++m)
      af[m] = *(const bf16x8*)((char*)As + (wr + m * 16 + lr) * 64 + lg * 16);
#pragma unroll
    for (int n = 0; n < 4; ++n)
      bfr[n] = *(const bf16x8*)((char*)Bs + (wc + n * 16 + lr) * 64 + lg * 16);
#pragma unroll
    for (int m = 0; m < 4; ++m)
#pragma unroll
      for (int n = 0; n < 4; ++n)
        acc[m][n] = __builtin_amdgcn_mfma_f32_16x16x32_bf16(af[m], bfr[n], acc[m][n], 0, 0, 0);
    __syncthreads();
  }
#pragma unroll
  for (int m = 0; m < 4; ++m)
#pragma unroll
    for (int n = 0; n < 4; ++n)
#pragma unroll
      for (int r = 0; r < 4; ++r) {
        const int row = m0 + wr + m * 16 + lg * 4 + r;
        const int col = n0 + wc + n * 16 + lr;
        if (OUT_MODE == 1) {
          ((float*)Cv)[(size_t)row * N + col] = acc[m][n][r];
        } else if (OUT_MODE == 0) {
          ((u16*)Cv)[(size_t)row * N + col] = f2bf(acc[m][n][r]);
        } else {  // fragment-tiled vtt
          const size_t adr = ((size_t)(row >> 4) * 256 + (col >> 5)) * 512 +
                             ((row & 15) + (((col >> 3) & 3) << 4)) * 8 + (col & 7);
          ((u16*)Cv)[adr] = f2bf(acc[m][n][r]);
        }
      }
}

// ---------------------------------------------------------------------------
// hi/lo 3-term MFMA GEMM for q,k (f32-equivalent accuracy).
// ---------------------------------------------------------------------------
__global__ __launch_bounds__(256, 2) void gemm_hilo(
    const u16* __restrict__ Ah, const u16* __restrict__ Al,
    const u16* __restrict__ BhQ, const u16* __restrict__ BlQ,
    u16* __restrict__ ChQ, u16* __restrict__ ClQ,
    const u16* __restrict__ BhK, const u16* __restrict__ BlK,
    u16* __restrict__ ChK, u16* __restrict__ ClK, int K) {
  const bool isQ = (blockIdx.x == 0);
  const u16* Bh = isQ ? BhQ : BhK;
  const u16* Bl = isQ ? BlQ : BlK;
  u16* Ch = isQ ? ChQ : ChK;
  u16* Cl = isQ ? ClQ : ClK;
  const float scale = isQ ? 11.31370849898476f : 1.0f;
  __shared__ __align__(16) u16 Ahs[64 * 32], Als[64 * 32];
  __shared__ __align__(16) u16 Bhs[128 * 32], Bls[128 * 32];
  const int tid = threadIdx.x;
  const int w = tid >> 6, l = tid & 63;
  const int lr = l & 15, lg = l >> 4;
  const int m0 = blockIdx.y * 64;
  const int wc = w * 32;

  f32x4 acc[4][2];
#pragma unroll
  for (int m = 0; m < 4; ++m)
#pragma unroll
    for (int n = 0; n < 2; ++n) {
      f32x4 z = {0.f, 0.f, 0.f, 0.f};
      acc[m][n] = z;
    }

  const int arow = w * 16 + (l >> 2);
  const int brow0 = (w * 2 + 0) * 16 + (l >> 2);
  const int brow1 = (w * 2 + 1) * 16 + (l >> 2);
  const int scol = (l & 3) * 8;

  for (int kt = 0; kt < K; kt += 32) {
    gload_lds16(Ah + (size_t)(m0 + arow) * K + kt + scol, (char*)Ahs + w * 1024);
    gload_lds16(Al + (size_t)(m0 + arow) * K + kt + scol, (char*)Als + w * 1024);
    gload_lds16(Bh + (size_t)brow0 * K + kt + scol, (char*)Bhs + (w * 2 + 0) * 1024);
    gload_lds16(Bh + (size_t)brow1 * K + kt + scol, (char*)Bhs + (w * 2 + 1) * 1024);
    gload_lds16(Bl + (size_t)brow0 * K + kt + scol, (char*)Bls + (w * 2 + 0) * 1024);
    gload_lds16(Bl + (size_t)brow1 * K + kt + scol, (char*)Bls + (w * 2 + 1) * 1024);
    __syncthreads();
    bf16x8 afh[4], afl[4], bfh[2], bfl[2];
#pragma unroll
    for (int m = 0; m < 4; ++m) {
      afh[m] = *(const bf16x8*)((char*)Ahs + (m * 16 + lr) * 64 + lg * 16);
      afl[m] = *(const bf16x8*)((char*)Als + (m * 16 + lr) * 64 + lg * 16);
    }
#pragma unroll
    for (int n = 0; n < 2; ++n) {
      bfh[n] = *(const bf16x8*)((char*)Bhs + (wc + n * 16 + lr) * 64 + lg * 16);
      bfl[n] = *(const bf16x8*)((char*)Bls + (wc + n * 16 + lr) * 64 + lg * 16);
    }
#pragma unroll
    for (int m = 0; m < 4; ++m)
#pragma unroll
      for (int n = 0; n < 2; ++n) {
        acc[m][n] = __builtin_amdgcn_mfma_f32_16x16x32_bf16(afh[m], bfh[n], acc[m][n], 0, 0, 0);
        acc[m][n] = __builtin_amdgcn_mfma_f32_16x16x32_bf16(afh[m], bfl[n], acc[m][n], 0, 0, 0);
        acc[m][n] = __builtin_amdgcn_mfma_f32_16x16x32_bf16(afl[m], bfh[n], acc[m][n], 0, 0, 0);
      }
    __syncthreads();
  }
#pragma unroll
  for (int m = 0; m < 4; ++m)
#pragma unroll
    for (int n = 0; n < 2; ++n)
#pragma unroll
      for (int r = 0; r < 4; ++r) {
        const size_t row = m0 + m * 16 + lg * 4 + r;
        const size_t col = wc + n * 16 + lr;
        const float v = acc[m][n][r] * scale;
        const u16 h = f2bf(v);
        Ch[row * 128 + col] = h;
        Cl[row * 128 + col] = f2bf(v - bf2f(h));
      }
}

// ---------------------------------------------------------------------------
__global__ __launch_bounds__(256) void cvt_bf16(const float* __restrict__ in,
                                                u16* __restrict__ out) {
  const size_t idx = (size_t)blockIdx.x * 256 + threadIdx.x;
  const float4 a = ((const float4*)in)[idx * 2];
  const float4 b = ((const float4*)in)[idx * 2 + 1];
  u16x8 o;
  o[0] = f2bf(a.x); o[1] = f2bf(a.y); o[2] = f2bf(a.z); o[3] = f2bf(a.w);
  o[4] = f2bf(b.x); o[5] = f2bf(b.y); o[6] = f2bf(b.z); o[7] = f2bf(b.w);
  ((u16x8*)out)[idx] = o;
}

__global__ __launch_bounds__(256) void split_hl(const float* __restrict__ in,
                                                u16* __restrict__ hi,
                                                u16* __restrict__ lo) {
  const size_t idx = (size_t)blockIdx.x * 256 + threadIdx.x;
  const float4 v = ((const float4*)in)[idx];
  float f[4] = {v.x, v.y, v.z, v.w};
  u16 h[4], g[4];
#pragma unroll
  for (int i = 0; i < 4; ++i) {
    h[i] = f2bf(f[i]);
    g[i] = f2bf(f[i] - bf2f(h[i]));
  }
  ushort4 hv; hv.x = h[0]; hv.y = h[1]; hv.z = h[2]; hv.w = h[3];
  ushort4 gv; gv.x = g[0]; gv.y = g[1]; gv.z = g[2]; gv.w = g[3];
  ((ushort4*)hi)[idx] = hv;
  ((ushort4*)lo)[idx] = gv;
}

// ---------------------------------------------------------------------------
// repack k hi/lo row-major [8192][128] -> MFMA-fragment-tiled (1 KB frags).
// ---------------------------------------------------------------------------
__global__ __launch_bounds__(256) void repack_k(const u16* __restrict__ krh,
                                                const u16* __restrict__ krl,
                                                u16* __restrict__ khT,
                                                u16* __restrict__ klT) {
  const int gid = blockIdx.x * 256 + threadIdx.x;
  const int f = gid >> 6, l = gid & 63;
  const int fn = f >> 2, fk = f & 3;
  const size_t src = (size_t)(fn * 16 + (l & 15)) * 128 + fk * 32 + (l >> 4) * 8;
  *(u16x8*)(khT + (size_t)f * 512 + l * 8) = *(const u16x8*)(krh + src);
  *(u16x8*)(klT + (size_t)f * 512 + l * 8) = *(const u16x8*)(krl + src);
}

// ---------------------------------------------------------------------------
// MFMA flash attention, KV-split (flash-decoding): grid (2 v-halves, 128 qb,
// 2 kv-halves) = 512 blocks x 8 waves. Each block: 32 of the 64 KV tiles.
// NO waves_per_eu attribute: with LDS 55.8 KB the compiler's own heuristic
// targets 2 blocks/CU (4 waves/EU -> 128-reg budget, our 108 fits) and the
// HW scheduler is free to pack 2 blocks/CU.
// Emits UNNORMALIZED O-partials (bf16, contiguous, z-half stride N_TOK*D_IN)
// + per-row m,l; combined downstream.
// ---------------------------------------------------------------------------
__global__ __launch_bounds__(512)
void flash_attn_mfma(const u16* __restrict__ qh, const u16* __restrict__ ql,
                     const u16* __restrict__ khT, const u16* __restrict__ klT,
                     const u16* __restrict__ vt, u16* __restrict__ part,
                     float* __restrict__ mfin, float* __restrict__ lfin) {
  __shared__ __align__(16) u16 Qs[2 * 8192];   // hi|lo, 64x128 swizzled (32 KB)
  __shared__ __align__(16) u16 P[64 * 128];    // 16 KB swizzled
  __shared__ __align__(16) float pmax[64][12];
  __shared__ __align__(16) float lpart[64][12];
  __shared__ __align__(16) float facl[64];
  const int tid = threadIdx.x;
  const int w = tid >> 6, l = tid & 63;
  const int lr = l & 15, lg = l >> 4;
  const int q0 = blockIdx.y * 64;
  const int half = blockIdx.x;
  const int z = blockIdx.z;       // kv-half
  const int tbase = z * 32;

  {  // stage Q hi/lo into swizzled LDS
#pragma unroll
    for (int i = 0; i < 2; ++i) {
      const int e = i * 512 + tid;  // 0..1023
      const int row = e >> 4, c16 = e & 15;
      const u16x8 hv = *(const u16x8*)(qh + (size_t)(q0 + row) * 128 + c16 * 8);
      const u16x8 lv = *(const u16x8*)(ql + (size_t)(q0 + row) * 128 + c16 * 8);
      const int b = (row * 256 + c16 * 16) ^ ((row & 7) << 4);
      *(u16x8*)((char*)Qs + b) = hv;
      *(u16x8*)((char*)Qs + 16384 + b) = lv;
    }
  }

  float mrun4[4] = {-INFINITY, -INFINITY, -INFINITY, -INFINITY};
  float lrun4[4] = {0.f, 0.f, 0.f, 0.f};

  f32x4 acc[4][4];
#pragma unroll
  for (int mt = 0; mt < 4; ++mt)
#pragma unroll
    for (int nt = 0; nt < 4; ++nt) {
      f32x4 z4 = {0.f, 0.f, 0.f, 0.f};
      acc[mt][nt] = z4;
    }

  bf16x8 kfh[4], kfl[4];
#pragma unroll
  for (int ks = 0; ks < 4; ++ks) {
    kfh[ks] = *(const bf16x8*)(khT + ((size_t)(tbase * 8 + w) * 4 + ks) * 512 + l * 8);
    kfl[ks] = *(const bf16x8*)(klT + ((size_t)(tbase * 8 + w) * 4 + ks) * 512 + l * 8);
  }
  __syncthreads();

  const int vcol0 = half * 32 + w * 4;

  for (int tt = 0; tt < 32; ++tt) {
    const int t = tbase + tt;
    const int c = t * 4;
    // ---- scores (swapped): sfT[mt][r] = S^T[k][q] ----
    f32x4 sfT[4];
#pragma unroll
    for (int mt = 0; mt < 4; ++mt) {
      f32x4 z4 = {0.f, 0.f, 0.f, 0.f};
      sfT[mt] = z4;
    }
    __builtin_amdgcn_s_setprio(1);
#pragma unroll
    for (int ks = 0; ks < 4; ++ks)
#pragma unroll
      for (int mt = 0; mt < 4; ++mt) {
        const int b = ((mt * 16 + lr) * 256 + ks * 64 + lg * 16) ^ ((lr & 7) << 4);
        const bf16x8 qfh = *(const bf16x8*)((char*)Qs + b);
        const bf16x8 qfl = *(const bf16x8*)((char*)Qs + 16384 + b);
        sfT[mt] = __builtin_amdgcn_mfma_f32_16x16x32_bf16(kfh[ks], qfh, sfT[mt], 0, 0, 0);
        sfT[mt] = __builtin_amdgcn_mfma_f32_16x16x32_bf16(kfl[ks], qfh, sfT[mt], 0, 0, 0);
        sfT[mt] = __builtin_amdgcn_mfma_f32_16x16x32_bf16(kfh[ks], qfl, sfT[mt], 0, 0, 0);
      }
    __builtin_amdgcn_s_setprio(0);
    // ---- early issue: K(t+1) + V(ks0) (land during softmax) ----
    if (tt < 31) {
#pragma unroll
      for (int ks = 0; ks < 4; ++ks) {
        kfh[ks] = *(const bf16x8*)(khT + ((size_t)((t + 1) * 8 + w) * 4 + ks) * 512 + l * 8);
        kfl[ks] = *(const bf16x8*)(klT + ((size_t)((t + 1) * 8 + w) * 4 + ks) * 512 + l * 8);
      }
    }
    bf16x8 vA[4], vB[4];
#pragma unroll
    for (int nt = 0; nt < 4; ++nt)
      vA[nt] = *(const bf16x8*)(vt + ((size_t)(vcol0 + nt) * 256 + c + 0) * 512 + l * 8);

    // ---- wave-slice max ----
    float wmax[4];
#pragma unroll
    for (int mt = 0; mt < 4; ++mt)
      wmax[mt] = fmaxf(fmaxf(sfT[mt][0], sfT[mt][1]), fmaxf(sfT[mt][2], sfT[mt][3]));
#pragma unroll
    for (int mt = 0; mt < 4; ++mt) {
      wmax[mt] = fmaxf(wmax[mt], __shfl_xor(wmax[mt], 16));
      wmax[mt] = fmaxf(wmax[mt], __shfl_xor(wmax[mt], 32));
    }
    if (lg == 0) {
#pragma unroll
      for (int mt = 0; mt < 4; ++mt) pmax[mt * 16 + lr][w] = wmax[mt];
    }
    __syncthreads();  // BAR1

    // ---- global max, fac, exp, pack P, wave-partial sum ----
    float mn4[4], fac4[4];
#pragma unroll
    for (int mt = 0; mt < 4; ++mt) {
      const int q = mt * 16 + lr;
      const f32x4 a = *(const f32x4*)&pmax[q][0];
      const f32x4 b = *(const f32x4*)&pmax[q][4];
      const float mx = fmaxf(fmaxf(fmaxf(a[0], a[1]), fmaxf(a[2], a[3])),
                             fmaxf(fmaxf(b[0], b[1]), fmaxf(b[2], b[3])));
      const float mn = fmaxf(mrun4[mt], mx);
      fac4[mt] = __expf(mrun4[mt] - mn);
      mn4[mt] = mn;
      mrun4[mt] = mn;
    }
    if (w == 0 && lg == 0) {
#pragma unroll
      for (int mt = 0; mt < 4; ++mt) facl[mt * 16 + lr] = fac4[mt];
    }
#pragma unroll
    for (int mt = 0; mt < 4; ++mt) {
      const float e0 = __expf(sfT[mt][0] - mn4[mt]);
      const float e1 = __expf(sfT[mt][1] - mn4[mt]);
      const float e2 = __expf(sfT[mt][2] - mn4[mt]);
      const float e3 = __expf(sfT[mt][3] - mn4[mt]);
      float tot = (e0 + e1) + (e2 + e3);
      tot += __shfl_xor(tot, 16);
      tot += __shfl_xor(tot, 32);
      lrun4[mt] = lrun4[mt] * fac4[mt] + tot;
      ushort4 pb;
      pb.x = f2bf(e0); pb.y = f2bf(e1); pb.z = f2bf(e2); pb.w = f2bf(e3);
      const int q = mt * 16 + lr;
      const int byte = (q * 256 + w * 32 + lg * 8) ^ ((q & 7) << 4);
      *(ushort4*)((char*)P + byte) = pb;
    }
    __syncthreads();  // BAR2

    // ---- rescale accumulators ----
#pragma unroll
    for (int mt = 0; mt < 4; ++mt) {
      const f32x4 f4 = *(const f32x4*)&facl[mt * 16 + lg * 4];
#pragma unroll
      for (int rr = 0; rr < 4; ++rr) {
        const float f = f4[rr];
        if (f != 1.0f) {
#pragma unroll
          for (int nt = 0; nt < 4; ++nt) acc[mt][nt][rr] *= f;
        }
      }
    }

    // ---- PV: 2-deep register ping-pong over ks ----
#pragma unroll
    for (int ks = 0; ks < 4; ++ks) {
      bf16x8* nxt = (ks & 1) ? vA : vB;
      if (ks < 3) {
#pragma unroll
        for (int nt = 0; nt < 4; ++nt)
          nxt[nt] = *(const bf16x8*)(vt + ((size_t)(vcol0 + nt) * 256 + c + ks + 1) * 512 + l * 8);
      }
      const bf16x8* cur = (ks & 1) ? vB : vA;
      bf16x8 pf[4];
#pragma unroll
      for (int mt = 0; mt < 4; ++mt) {
        const int row = mt * 16 + lr;
        pf[mt] = *(const bf16x8*)((char*)P + ((row * 256 + ks * 64 + lg * 16) ^ ((row & 7) << 4)));
      }
      __builtin_amdgcn_s_setprio(1);
#pragma unroll
      for (int mt = 0; mt < 4; ++mt)
#pragma unroll
        for (int nt = 0; nt < 4; ++nt)
          acc[mt][nt] = __builtin_amdgcn_mfma_f32_16x16x32_bf16(pf[mt], cur[nt], acc[mt][nt], 0, 0, 0);
      __builtin_amdgcn_s_setprio(0);
    }
  }
  // ---- epilogue: write unnormalized partials (bf16) + m,l ----
  if (lg == 0) {
#pragma unroll
    for (int mt = 0; mt < 4; ++mt) lpart[mt * 16 + lr][w] = lrun4[mt];
  }
  if (w == 0 && lg == 0) {
#pragma unroll
    for (int mt = 0; mt < 4; ++mt)
      mfin[(size_t)z * N_TOK + q0 + mt * 16 + lr] = mrun4[mt];
  }
  __syncthreads();
  u16* pz = part + (size_t)z * N_TOK * D_IN;
#pragma unroll
  for (int mt = 0; mt < 4; ++mt)
#pragma unroll
    for (int rr = 0; rr < 4; ++rr) {
      const int row = mt * 16 + lg * 4 + rr;
      const f32x4 a = *(const f32x4*)&lpart[row][0];
      const f32x4 b = *(const f32x4*)&lpart[row][4];
      const float lsum =
          ((a[0] + a[1]) + (a[2] + a[3])) + ((b[0] + b[1]) + (b[2] + b[3]));
      if (w == 0 && lr == 0) lfin[(size_t)z * N_TOK + q0 + row] = lsum;
#pragma unroll
      for (int nt = 0; nt < 4; ++nt)
        pz[(size_t)(q0 + row) * 1024 + half * 512 + w * 64 + nt * 16 + lr] =
            f2bf(acc[mt][nt][rr]);
    }
}

// ---------------------------------------------------------------------------
// Combine kv-half partials + residual + LayerNorm (fused):
// sa = (e^{m0-m} O~0 + e^{m1-m} O~1) / (e^{m0-m} l0 + e^{m1-m} l1)
// writes sa (bf16, for the final LN) and h = LN(x + sa) (bf16).
// ---------------------------------------------------------------------------
__global__ __launch_bounds__(256) void comb_ln(const u16* __restrict__ part,
                                               const float* __restrict__ mfin,
                                               const float* __restrict__ lfin,
                                               const float* __restrict__ x,
                                               u16* __restrict__ sa_bf,
                                               u16* __restrict__ hb) {
  const int row = blockIdx.x;
  const int tid = threadIdx.x;
  const size_t base = (size_t)row * 256 + tid;
  const float m0 = mfin[row], m1 = mfin[N_TOK + row];
  const float l0 = lfin[row], l1 = lfin[N_TOK + row];
  const float m = fmaxf(m0, m1);
  const float a0 = __expf(m0 - m), a1 = __expf(m1 - m);
  const float inv = 1.0f / (a0 * l0 + a1 * l1);
  const float s0 = a0 * inv, s1 = a1 * inv;
  const ushort4 p0 = ((const ushort4*)part)[base];
  const ushort4 p1 = ((const ushort4*)(part + (size_t)N_TOK * D_IN))[base];
  float o0 = s0 * bf2f(p0.x) + s1 * bf2f(p1.x);
  float o1 = s0 * bf2f(p0.y) + s1 * bf2f(p1.y);
  float o2 = s0 * bf2f(p0.z) + s1 * bf2f(p1.z);
  float o3 = s0 * bf2f(p0.w) + s1 * bf2f(p1.w);
  ushort4 sv;
  sv.x = f2bf(o0); sv.y = f2bf(o1); sv.z = f2bf(o2); sv.w = f2bf(o3);
  ((ushort4*)sa_bf)[base] = sv;
  const float4 xv = ((const float4*)x)[base];
  float4 y;
  y.x = xv.x + o0; y.y = xv.y + o1; y.z = xv.z + o2; y.w = xv.w + o3;
  float s1r = y.x + y.y + y.z + y.w;
  float s2r = y.x * y.x + y.y * y.y + y.z * y.z + y.w * y.w;
#pragma unroll
  for (int off = 32; off > 0; off >>= 1) {
    s1r += __shfl_xor(s1r, off);
    s2r += __shfl_xor(s2r, off);
  }
  __shared__ float r1[4];
  __shared__ float r2[4];
  if ((tid & 63) == 0) { r1[tid >> 6] = s1r; r2[tid >> 6] = s2r; }
  __syncthreads();
  s1r = r1[0] + r1[1] + r1[2] + r1[3];
  s2r = r2[0] + r2[1] + r2[2] + r2[3];
  const float mu = s1r * (1.0f / 1024.0f);
  const float var = s2r * (1.0f / 1024.0f) - mu * mu;
  const float rs = rsqrtf(var + 1e-5f);
  ushort4 ov;
  ov.x = f2bf((y.x - mu) * rs); ov.y = f2bf((y.y - mu) * rs);
  ov.z = f2bf((y.z - mu) * rs); ov.w = f2bf((y.w - mu) * rs);
  ((ushort4*)hb)[base] = ov;
}

// ---------------------------------------------------------------------------
// out(f32) = LayerNorm(sa_bf16 + out) over last dim 1024, in place.
// ---------------------------------------------------------------------------
__global__ __launch_bounds__(256) void ln_final(const u16* __restrict__ sa_bf,
                                                float* __restrict__ o) {
  const int row = blockIdx.x;
  const int tid = threadIdx.x;
  const size_t base = (size_t)row * 256 + tid;
  const ushort4 sv = ((const ushort4*)sa_bf)[base];
  const float4 ov = ((const float4*)o)[base];
  float4 y;
  y.x = ov.x + bf2f(sv.x); y.y = ov.y + bf2f(sv.y);
  y.z = ov.z + bf2f(sv.z); y.w = ov.w + bf2f(sv.w);
  float s1 = y.x + y.y + y.z + y.w;
  float s2 = y.x * y.x + y.y * y.y + y.z * y.z + y.w * y.w;
#pragma unroll
  for (int off = 32; off > 0; off >>= 1) {
    s1 += __shfl_xor(s1, off);
    s2 += __shfl_xor(s2, off);
  }
  __shared__ float r1[4];
  __shared__ float r2[4];
  if ((tid & 63) == 0) { r1[tid >> 6] = s1; r2[tid >> 6] = s2; }
  __syncthreads();
  s1 = r1[0] + r1[1] + r1[2] + r1[3];
  s2 = r2[0] + r2[1] + r2[2] + r2[3];
  const float mu = s1 * (1.0f / 1024.0f);
  const float var = s2 * (1.0f / 1024.0f) - mu * mu;
  const float rs = rsqrtf(var + 1e-5f);
  float4 res;
  res.x = (y.x - mu) * rs; res.y = (y.y - mu) * rs;
  res.z = (y.z - mu) * rs; res.w = (y.w - mu) * rs;
  ((float4*)o)[base] = res;
}

// ---------------------------------------------------------------------------
extern "C" void kernel_launch(void* const* d_in, const int* in_sizes, int n_in,
                              void* d_out, int out_size, void* d_ws, size_t ws_size,
                              hipStream_t stream) {
  const float* x  = (const float*)d_in[0];
  const float* Wq = (const float*)d_in[1];
  const float* Wk = (const float*)d_in[2];
  const float* Wv = (const float*)d_in[3];
  const float* Wl = (const float*)d_in[4];
  float* out = (float*)d_out;

  // workspace layout (<=100 MB), lifetime-aliased (verified round 17):
  //  0-16 : xh (dead after gemm_hilo) -> sa_bf
  // 16-20 : khT/klT [live during flash]
  // 20-36 : hb@20; qh@32, ql@34 [live in flash]
  // 36-40 : krh/krl -> mfin/lfin after repack_k
  // 40-44 : wq/wk splits
  // 48-64 : vtt [live during flash]
  // 64-96 : part (contiguous 32 MB)
  // 96-100: Wvb, Wlb
  char* w8 = (char*)d_ws;
  u16* xh    = (u16*)(w8 + (0ull << 20));
  u16* xl    = (u16*)(w8 + (16ull << 20));
  u16* khT   = (u16*)(w8 + (16ull << 20));
  u16* klT   = (u16*)(w8 + (18ull << 20));
  u16* sa_bf = (u16*)(w8 + (0ull << 20));
  u16* hb    = (u16*)(w8 + (20ull << 20));
  u16* qh    = (u16*)(w8 + (32ull << 20));
  u16* ql    = (u16*)(w8 + (34ull << 20));
  u16* krh   = (u16*)(w8 + (36ull << 20));
  u16* krl   = (u16*)(w8 + (38ull << 20));
  float* mfin = (float*)(w8 + (36ull << 20));
  float* lfin = (float*)(w8 + (36ull << 20) + (128ull << 10));
  u16* wqh = (u16*)(w8 + (40ull << 20));
  u16* wql = (u16*)(w8 + (40ull << 20) + (256ull << 10));
  u16* wkh = (u16*)(w8 + (40ull << 20) + (512ull << 10));
  u16* wkl = (u16*)(w8 + (40ull << 20) + (768ull << 10));
  u16* vtt   = (u16*)(w8 + (48ull << 20));
  u16* part  = (u16*)(w8 + (64ull << 20));  // contiguous 32 MB
  u16* Wvb = (u16*)(w8 + (96ull << 20));
  u16* Wlb = (u16*)(w8 + (98ull << 20));

  split_hl<<<8192, 256, 0, stream>>>(x, xh, xl);
  cvt_bf16<<<512, 256, 0, stream>>>(Wv, Wvb);
  cvt_bf16<<<512, 256, 0, stream>>>(Wl, Wlb);
  // v-GEMM writes the fragment-tiled vtt directly (mode 2).
  gemm_mfma<2><<<dim3(64, 8), 256, 0, stream>>>(Wvb, xh, (void*)vtt, D_IN, N_TOK, D_IN);
  split_hl<<<128, 256, 0, stream>>>(Wq, wqh, wql);
  split_hl<<<128, 256, 0, stream>>>(Wk, wkh, wkl);
  gemm_hilo<<<dim3(2, 128), 256, 0, stream>>>(xh, xl, wqh, wql, qh, ql,
                                              wkh, wkl, krh, krl, D_IN);
  repack_k<<<512, 256, 0, stream>>>(krh, krl, khT, klT);
  // KV-split flash: 512 blocks, unnormalized partials per kv-half.
  flash_attn_mfma<<<dim3(2, 128, 2), 512, 0, stream>>>(qh, ql, khT, klT, vtt,
                                                       part, mfin, lfin);
  // combine + residual + LN1 (fused); emits sa (bf16) and h (bf16).
  comb_ln<<<N_TOK, 256, 0, stream>>>(part, mfin, lfin, x, sa_bf, hb);
  gemm_mfma<1><<<dim3(8, 64), 256, 0, stream>>>(hb, Wlb, (void*)out, N_TOK, D_IN, D_IN);
  ln_final<<<N_TOK, 256, 0, stream>>>(sa_bf, out);
}

// Round 19
// 397.047 us; speedup vs baseline: 1.0551x; 1.0549x over previous
//
#include <hip/hip_runtime.h>
#include <hip/hip_bf16.h>
#include <math.h>

#define N_TOK 8192
#define D_IN  1024
#define D_QK  128

typedef short bf16x8 __attribute__((ext_vector_type(8)));
typedef float f32x4 __attribute__((ext_vector_type(4)));
typedef unsigned short u16;
typedef u16 u16x8 __attribute__((ext_vector_type(8)));

static __device__ __forceinline__ u16 f2bf(float f) {
  __hip_bfloat16 b = __float2bfloat16(f);
  return *(u16*)&b;
}
static __device__ __forceinline__ float bf2f(u16 u) {
  __hip_bfloat16 b = *(__hip_bfloat16*)&u;
  return __bfloat162float(b);
}

static __device__ __forceinline__ void gload_lds16(const void* g, void* lds) {
  __builtin_amdgcn_global_load_lds(
      (const __attribute__((address_space(1))) unsigned int*)g,
      (__attribute__((address_space(3))) unsigned int*)lds, 16, 0, 0);
}

// ---------------------------------------------------------------------------
// bf16 MFMA GEMM: C[M][N] = A[M][K] * B[N][K]^T, 128x128 tile, BK=32.
// OUT_MODE: 0 = bf16 row-major, 1 = f32 row-major, 2 = bf16 frag-tiled vtt.
// ---------------------------------------------------------------------------
template <int OUT_MODE>
__global__ __launch_bounds__(256, 2) void gemm_mfma(const u16* __restrict__ A,
                                                    const u16* __restrict__ B,
                                                    void* __restrict__ Cv,
                                                    int M, int N, int K) {
  __shared__ __align__(16) u16 As[128 * 32];
  __shared__ __align__(16) u16 Bs[128 * 32];
  const int tid = threadIdx.x;
  const int w = tid >> 6, l = tid & 63;
  const int lr = l & 15, lg = l >> 4;
  const int m0 = blockIdx.y * 128, n0 = blockIdx.x * 128;
  const int wr = (w >> 1) * 64, wc = (w & 1) * 64;

  f32x4 acc[4][4];
#pragma unroll
  for (int m = 0; m < 4; ++m)
#pragma unroll
    for (int n = 0; n < 4; ++n) {
      f32x4 z = {0.f, 0.f, 0.f, 0.f};
      acc[m][n] = z;
    }

  const int ldsb0 = (w * 2 + 0) * 1024;
  const int ldsb1 = (w * 2 + 1) * 1024;
  const int srow0 = (w * 2 + 0) * 16 + (l >> 2);
  const int srow1 = (w * 2 + 1) * 16 + (l >> 2);
  const int scol = (l & 3) * 8;

  for (int kt = 0; kt < K; kt += 32) {
    gload_lds16(A + (size_t)(m0 + srow0) * K + kt + scol, (char*)As + ldsb0);
    gload_lds16(A + (size_t)(m0 + srow1) * K + kt + scol, (char*)As + ldsb1);
    gload_lds16(B + (size_t)(n0 + srow0) * K + kt + scol, (char*)Bs + ldsb0);
    gload_lds16(B + (size_t)(n0 + srow1) * K + kt + scol, (char*)Bs + ldsb1);
    __syncthreads();
    bf16x8 af[4], bfr[4];
#pragma unroll
    for (int m = 0; m < 4; ++m)
      af[m] = *(const bf16x8*)((char*)As + (wr + m * 16 + lr) * 64 + lg * 16);
#pragma unroll
    for (int n = 0; n < 4; ++n)
      bfr[n] = *(const bf16x8*)((char*)Bs + (wc + n * 16 + lr) * 64 + lg * 16);
#pragma unroll
    for (int m = 0; m < 4; ++m)
#pragma unroll
      for (int n = 0; n < 4; ++n)
        acc[m][n] = __builtin_amdgcn_mfma_f32_16x16x32_bf16(af[m], bfr[n], acc[m][n], 0, 0, 0);
    __syncthreads();
  }
#pragma unroll
  for (int m = 0; m < 4; ++m)
#pragma unroll
    for (int n = 0; n < 4; ++n)
#pragma unroll
      for (int r = 0; r < 4; ++r) {
        const int row = m0 + wr + m * 16 + lg * 4 + r;
        const int col = n0 + wc + n * 16 + lr;
        if (OUT_MODE == 1) {
          ((float*)Cv)[(size_t)row * N + col] = acc[m][n][r];
        } else if (OUT_MODE == 0) {
          ((u16*)Cv)[(size_t)row * N + col] = f2bf(acc[m][n][r]);
        } else {  // fragment-tiled vtt
          const size_t adr = ((size_t)(row >> 4) * 256 + (col >> 5)) * 512 +
                             ((row & 15) + (((col >> 3) & 3) << 4)) * 8 + (col & 7);
          ((u16*)Cv)[adr] = f2bf(acc[m][n][r]);
        }
      }
}

// ---------------------------------------------------------------------------
// hi/lo 3-term MFMA GEMM for q,k (f32-equivalent accuracy).
// ---------------------------------------------------------------------------
__global__ __launch_bounds__(256, 2) void gemm_hilo(
    const u16* __restrict__ Ah, const u16* __restrict__ Al,
    const u16* __restrict__ BhQ, const u16* __restrict__ BlQ,
    u16* __restrict__ ChQ, u16* __restrict__ ClQ,
    const u16* __restrict__ BhK, const u16* __restrict__ BlK,
    u16* __restrict__ ChK, u16* __restrict__ ClK, int K) {
  const bool isQ = (blockIdx.x == 0);
  const u16* Bh = isQ ? BhQ : BhK;
  const u16* Bl = isQ ? BlQ : BlK;
  u16* Ch = isQ ? ChQ : ChK;
  u16* Cl = isQ ? ClQ : ClK;
  const float scale = isQ ? 11.31370849898476f : 1.0f;
  __shared__ __align__(16) u16 Ahs[64 * 32], Als[64 * 32];
  __shared__ __align__(16) u16 Bhs[128 * 32], Bls[128 * 32];
  const int tid = threadIdx.x;
  const int w = tid >> 6, l = tid & 63;
  const int lr = l & 15, lg = l >> 4;
  const int m0 = blockIdx.y * 64;
  const int wc = w * 32;

  f32x4 acc[4][2];
#pragma unroll
  for (int m = 0; m < 4; ++m)
#pragma unroll
    for (int n = 0; n < 2; ++n) {
      f32x4 z = {0.f, 0.f, 0.f, 0.f};
      acc[m][n] = z;
    }

  const int arow = w * 16 + (l >> 2);
  const int brow0 = (w * 2 + 0) * 16 + (l >> 2);
  const int brow1 = (w * 2 + 1) * 16 + (l >> 2);
  const int scol = (l & 3) * 8;

  for (int kt = 0; kt < K; kt += 32) {
    gload_lds16(Ah + (size_t)(m0 + arow) * K + kt + scol, (char*)Ahs + w * 1024);
    gload_lds16(Al + (size_t)(m0 + arow) * K + kt + scol, (char*)Als + w * 1024);
    gload_lds16(Bh + (size_t)brow0 * K + kt + scol, (char*)Bhs + (w * 2 + 0) * 1024);
    gload_lds16(Bh + (size_t)brow1 * K + kt + scol, (char*)Bhs + (w * 2 + 1) * 1024);
    gload_lds16(Bl + (size_t)brow0 * K + kt + scol, (char*)Bls + (w * 2 + 0) * 1024);
    gload_lds16(Bl + (size_t)brow1 * K + kt + scol, (char*)Bls + (w * 2 + 1) * 1024);
    __syncthreads();
    bf16x8 afh[4], afl[4], bfh[2], bfl[2];
#pragma unroll
    for (int m = 0; m < 4; ++m) {
      afh[m] = *(const bf16x8*)((char*)Ahs + (m * 16 + lr) * 64 + lg * 16);
      afl[m] = *(const bf16x8*)((char*)Als + (m * 16 + lr) * 64 + lg * 16);
    }
#pragma unroll
    for (int n = 0; n < 2; ++n) {
      bfh[n] = *(const bf16x8*)((char*)Bhs + (wc + n * 16 + lr) * 64 + lg * 16);
      bfl[n] = *(const bf16x8*)((char*)Bls + (wc + n * 16 + lr) * 64 + lg * 16);
    }
#pragma unroll
    for (int m = 0; m < 4; ++m)
#pragma unroll
      for (int n = 0; n < 2; ++n) {
        acc[m][n] = __builtin_amdgcn_mfma_f32_16x16x32_bf16(afh[m], bfh[n], acc[m][n], 0, 0, 0);
        acc[m][n] = __builtin_amdgcn_mfma_f32_16x16x32_bf16(afh[m], bfl[n], acc[m][n], 0, 0, 0);
        acc[m][n] = __builtin_amdgcn_mfma_f32_16x16x32_bf16(afl[m], bfh[n], acc[m][n], 0, 0, 0);
      }
    __syncthreads();
  }
#pragma unroll
  for (int m = 0; m < 4; ++m)
#pragma unroll
    for (int n = 0; n < 2; ++n)
#pragma unroll
      for (int r = 0; r < 4; ++r) {
        const size_t row = m0 + m * 16 + lg * 4 + r;
        const size_t col = wc + n * 16 + lr;
        const float v = acc[m][n][r] * scale;
        const u16 h = f2bf(v);
        Ch[row * 128 + col] = h;
        Cl[row * 128 + col] = f2bf(v - bf2f(h));
      }
}

// ---------------------------------------------------------------------------
__global__ __launch_bounds__(256) void cvt_bf16(const float* __restrict__ in,
                                                u16* __restrict__ out) {
  const size_t idx = (size_t)blockIdx.x * 256 + threadIdx.x;
  const float4 a = ((const float4*)in)[idx * 2];
  const float4 b = ((const float4*)in)[idx * 2 + 1];
  u16x8 o;
  o[0] = f2bf(a.x); o[1] = f2bf(a.y); o[2] = f2bf(a.z); o[3] = f2bf(a.w);
  o[4] = f2bf(b.x); o[5] = f2bf(b.y); o[6] = f2bf(b.z); o[7] = f2bf(b.w);
  ((u16x8*)out)[idx] = o;
}

__global__ __launch_bounds__(256) void split_hl(const float* __restrict__ in,
                                                u16* __restrict__ hi,
                                                u16* __restrict__ lo) {
  const size_t idx = (size_t)blockIdx.x * 256 + threadIdx.x;
  const float4 v = ((const float4*)in)[idx];
  float f[4] = {v.x, v.y, v.z, v.w};
  u16 h[4], g[4];
#pragma unroll
  for (int i = 0; i < 4; ++i) {
    h[i] = f2bf(f[i]);
    g[i] = f2bf(f[i] - bf2f(h[i]));
  }
  ushort4 hv; hv.x = h[0]; hv.y = h[1]; hv.z = h[2]; hv.w = h[3];
  ushort4 gv; gv.x = g[0]; gv.y = g[1]; gv.z = g[2]; gv.w = g[3];
  ((ushort4*)hi)[idx] = hv;
  ((ushort4*)lo)[idx] = gv;
}

// ---------------------------------------------------------------------------
// repack k hi/lo row-major [8192][128] -> MFMA-fragment-tiled (1 KB frags).
// ---------------------------------------------------------------------------
__global__ __launch_bounds__(256) void repack_k(const u16* __restrict__ krh,
                                                const u16* __restrict__ krl,
                                                u16* __restrict__ khT,
                                                u16* __restrict__ klT) {
  const int gid = blockIdx.x * 256 + threadIdx.x;
  const int f = gid >> 6, l = gid & 63;
  const int fn = f >> 2, fk = f & 3;
  const size_t src = (size_t)(fn * 16 + (l & 15)) * 128 + fk * 32 + (l >> 4) * 8;
  *(u16x8*)(khT + (size_t)f * 512 + l * 8) = *(const u16x8*)(krh + src);
  *(u16x8*)(klT + (size_t)f * 512 + l * 8) = *(const u16x8*)(krl + src);
}

// ---------------------------------------------------------------------------
// MFMA flash attention (round-13/14 measured optimum: flash 279 us, VGPR 108,
// no spills). Swapped-operand scores (S^T = mfma(K,Q)) -> k-axis lane-local
// -> in-register softmax. grid = (2 halves, 128 q-blocks) x 512 threads
// (8 waves). Block (h, qb): q-rows qb*64..+63, v-cols h*512..+511. KVBLK=128.
// m/l state in registers; cross-wave max via pmax LDS; l combined at end.
// K prefetched 1 tile ahead; V 2-deep ping-pong.
// NOTE: waves_per_eu(2,2) is the measured-best occupancy config; 2-blocks/CU
// is unreachable for 8-wave groups on this toolchain (rounds 15-18 probes).
// ---------------------------------------------------------------------------
__global__ __launch_bounds__(512) __attribute__((amdgpu_waves_per_eu(2, 2)))
void flash_attn_mfma(const u16* __restrict__ qh, const u16* __restrict__ ql,
                     const u16* __restrict__ khT, const u16* __restrict__ klT,
                     const u16* __restrict__ vt, float* __restrict__ sa) {
  __shared__ __align__(16) u16 Qs[2 * 8192];   // hi|lo, 64x128 swizzled (32 KB)
  __shared__ __align__(16) u16 P[64 * 128];    // 16 KB swizzled
  __shared__ __align__(16) float pmax[64][12];
  __shared__ __align__(16) float lpart[64][12];
  __shared__ __align__(16) float facl[64];
  const int tid = threadIdx.x;
  const int w = tid >> 6, l = tid & 63;
  const int lr = l & 15, lg = l >> 4;
  const int q0 = blockIdx.y * 64;
  const int half = blockIdx.x;

  {  // stage Q hi/lo into swizzled LDS
#pragma unroll
    for (int i = 0; i < 2; ++i) {
      const int e = i * 512 + tid;  // 0..1023
      const int row = e >> 4, c16 = e & 15;
      const u16x8 hv = *(const u16x8*)(qh + (size_t)(q0 + row) * 128 + c16 * 8);
      const u16x8 lv = *(const u16x8*)(ql + (size_t)(q0 + row) * 128 + c16 * 8);
      const int b = (row * 256 + c16 * 16) ^ ((row & 7) << 4);
      *(u16x8*)((char*)Qs + b) = hv;
      *(u16x8*)((char*)Qs + 16384 + b) = lv;
    }
  }

  // per-lane online-softmax state: rows mt*16+lr (4 rows per lane)
  float mrun4[4] = {-INFINITY, -INFINITY, -INFINITY, -INFINITY};
  float lrun4[4] = {0.f, 0.f, 0.f, 0.f};  // wave-partial (this wave's k-slices)

  f32x4 acc[4][4];
#pragma unroll
  for (int mt = 0; mt < 4; ++mt)
#pragma unroll
    for (int nt = 0; nt < 4; ++nt) {
      f32x4 z = {0.f, 0.f, 0.f, 0.f};
      acc[mt][nt] = z;
    }

  bf16x8 kfh[4], kfl[4];
#pragma unroll
  for (int ks = 0; ks < 4; ++ks) {
    kfh[ks] = *(const bf16x8*)(khT + ((size_t)w * 4 + ks) * 512 + l * 8);
    kfl[ks] = *(const bf16x8*)(klT + ((size_t)w * 4 + ks) * 512 + l * 8);
  }
  __syncthreads();

  const int vcol0 = half * 32 + w * 4;

  for (int t = 0; t < 64; ++t) {
    const int c = t * 4;
    // ---- scores (swapped): sfT[mt][r] = S^T[k = w*16+lg*4+r][q = mt*16+lr] ----
    f32x4 sfT[4];
#pragma unroll
    for (int mt = 0; mt < 4; ++mt) {
      f32x4 z = {0.f, 0.f, 0.f, 0.f};
      sfT[mt] = z;
    }
    __builtin_amdgcn_s_setprio(1);
#pragma unroll
    for (int ks = 0; ks < 4; ++ks)
#pragma unroll
      for (int mt = 0; mt < 4; ++mt) {
        const int b = ((mt * 16 + lr) * 256 + ks * 64 + lg * 16) ^ ((lr & 7) << 4);
        const bf16x8 qfh = *(const bf16x8*)((char*)Qs + b);
        const bf16x8 qfl = *(const bf16x8*)((char*)Qs + 16384 + b);
        sfT[mt] = __builtin_amdgcn_mfma_f32_16x16x32_bf16(kfh[ks], qfh, sfT[mt], 0, 0, 0);
        sfT[mt] = __builtin_amdgcn_mfma_f32_16x16x32_bf16(kfl[ks], qfh, sfT[mt], 0, 0, 0);
        sfT[mt] = __builtin_amdgcn_mfma_f32_16x16x32_bf16(kfh[ks], qfl, sfT[mt], 0, 0, 0);
      }
    __builtin_amdgcn_s_setprio(0);
    // ---- early issue: K(t+1) + V(ks0) (land during softmax) ----
    if (t < 63) {
#pragma unroll
      for (int ks = 0; ks < 4; ++ks) {
        kfh[ks] = *(const bf16x8*)(khT + ((size_t)((t + 1) * 8 + w) * 4 + ks) * 512 + l * 8);
        kfl[ks] = *(const bf16x8*)(klT + ((size_t)((t + 1) * 8 + w) * 4 + ks) * 512 + l * 8);
      }
    }
    bf16x8 vA[4], vB[4];
#pragma unroll
    for (int nt = 0; nt < 4; ++nt)
      vA[nt] = *(const bf16x8*)(vt + ((size_t)(vcol0 + nt) * 256 + c + 0) * 512 + l * 8);

    // ---- wave-slice max: lane-local over 4 k, then cross-lane shfl ----
    float wmax[4];
#pragma unroll
    for (int mt = 0; mt < 4; ++mt)
      wmax[mt] = fmaxf(fmaxf(sfT[mt][0], sfT[mt][1]), fmaxf(sfT[mt][2], sfT[mt][3]));
#pragma unroll
    for (int mt = 0; mt < 4; ++mt) {
      wmax[mt] = fmaxf(wmax[mt], __shfl_xor(wmax[mt], 16));
      wmax[mt] = fmaxf(wmax[mt], __shfl_xor(wmax[mt], 32));
    }
    if (lg == 0) {
#pragma unroll
      for (int mt = 0; mt < 4; ++mt) pmax[mt * 16 + lr][w] = wmax[mt];
    }
    __syncthreads();  // BAR1

    // ---- global max, fac, exp, pack P, wave-partial sum (all in regs) ----
    float mn4[4], fac4[4];
#pragma unroll
    for (int mt = 0; mt < 4; ++mt) {
      const int q = mt * 16 + lr;
      const f32x4 a = *(const f32x4*)&pmax[q][0];
      const f32x4 b = *(const f32x4*)&pmax[q][4];
      const float mx = fmaxf(fmaxf(fmaxf(a[0], a[1]), fmaxf(a[2], a[3])),
                             fmaxf(fmaxf(b[0], b[1]), fmaxf(b[2], b[3])));
      const float mn = fmaxf(mrun4[mt], mx);
      fac4[mt] = __expf(mrun4[mt] - mn);
      mn4[mt] = mn;
      mrun4[mt] = mn;
    }
    if (w == 0 && lg == 0) {
#pragma unroll
      for (int mt = 0; mt < 4; ++mt) facl[mt * 16 + lr] = fac4[mt];
    }
#pragma unroll
    for (int mt = 0; mt < 4; ++mt) {
      const float e0 = __expf(sfT[mt][0] - mn4[mt]);
      const float e1 = __expf(sfT[mt][1] - mn4[mt]);
      const float e2 = __expf(sfT[mt][2] - mn4[mt]);
      const float e3 = __expf(sfT[mt][3] - mn4[mt]);
      float tot = (e0 + e1) + (e2 + e3);
      tot += __shfl_xor(tot, 16);
      tot += __shfl_xor(tot, 32);
      lrun4[mt] = lrun4[mt] * fac4[mt] + tot;
      ushort4 pb;
      pb.x = f2bf(e0); pb.y = f2bf(e1); pb.z = f2bf(e2); pb.w = f2bf(e3);
      const int q = mt * 16 + lr;
      const int byte = (q * 256 + w * 32 + lg * 8) ^ ((q & 7) << 4);
      *(ushort4*)((char*)P + byte) = pb;
    }
    __syncthreads();  // BAR2

    // ---- rescale accumulators ----
#pragma unroll
    for (int mt = 0; mt < 4; ++mt) {
      const f32x4 f4 = *(const f32x4*)&facl[mt * 16 + lg * 4];
#pragma unroll
      for (int rr = 0; rr < 4; ++rr) {
        const float f = f4[rr];
        if (f != 1.0f) {
#pragma unroll
          for (int nt = 0; nt < 4; ++nt) acc[mt][nt][rr] *= f;
        }
      }
    }

    // ---- PV: 2-deep register ping-pong over ks (only chunk0 preloaded) ----
#pragma unroll
    for (int ks = 0; ks < 4; ++ks) {
      bf16x8* nxt = (ks & 1) ? vA : vB;
      if (ks < 3) {
#pragma unroll
        for (int nt = 0; nt < 4; ++nt)
          nxt[nt] = *(const bf16x8*)(vt + ((size_t)(vcol0 + nt) * 256 + c + ks + 1) * 512 + l * 8);
      }
      const bf16x8* cur = (ks & 1) ? vB : vA;
      bf16x8 pf[4];
#pragma unroll
      for (int mt = 0; mt < 4; ++mt) {
        const int row = mt * 16 + lr;
        pf[mt] = *(const bf16x8*)((char*)P + ((row * 256 + ks * 64 + lg * 16) ^ ((row & 7) << 4)));
      }
      __builtin_amdgcn_s_setprio(1);
#pragma unroll
      for (int mt = 0; mt < 4; ++mt)
#pragma unroll
        for (int nt = 0; nt < 4; ++nt)
          acc[mt][nt] = __builtin_amdgcn_mfma_f32_16x16x32_bf16(pf[mt], cur[nt], acc[mt][nt], 0, 0, 0);
      __builtin_amdgcn_s_setprio(0);
    }
  }
  // ---- combine wave-partial l, epilogue ----
  if (lg == 0) {
#pragma unroll
    for (int mt = 0; mt < 4; ++mt) lpart[mt * 16 + lr][w] = lrun4[mt];
  }
  __syncthreads();
#pragma unroll
  for (int mt = 0; mt < 4; ++mt)
#pragma unroll
    for (int rr = 0; rr < 4; ++rr) {
      const int row = mt * 16 + lg * 4 + rr;
      const f32x4 a = *(const f32x4*)&lpart[row][0];
      const f32x4 b = *(const f32x4*)&lpart[row][4];
      const float inv =
          1.0f / (((a[0] + a[1]) + (a[2] + a[3])) + ((b[0] + b[1]) + (b[2] + b[3])));
#pragma unroll
      for (int nt = 0; nt < 4; ++nt)
        sa[(size_t)(q0 + row) * 1024 + half * 512 + w * 64 + nt * 16 + lr] =
            acc[mt][nt][rr] * inv;
    }
}

// ---------------------------------------------------------------------------
// out(f32) = LayerNorm(a + b) over last dim 1024. Safe with o == b.
// ---------------------------------------------------------------------------
__global__ __launch_bounds__(256) void ln_add(const float* __restrict__ a,
                                              const float* __restrict__ b,
                                              float* __restrict__ o) {
  const int row = blockIdx.x;
  const int tid = threadIdx.x;
  const size_t base = (size_t)row * 256 + tid;
  const float4 av = ((const float4*)a)[base];
  const float4 bv = ((const float4*)b)[base];
  float4 y;
  y.x = av.x + bv.x; y.y = av.y + bv.y;
  y.z = av.z + bv.z; y.w = av.w + bv.w;
  float s1 = y.x + y.y + y.z + y.w;
  float s2 = y.x * y.x + y.y * y.y + y.z * y.z + y.w * y.w;
#pragma unroll
  for (int off = 32; off > 0; off >>= 1) {
    s1 += __shfl_xor(s1, off);
    s2 += __shfl_xor(s2, off);
  }
  __shared__ float r1[4];
  __shared__ float r2[4];
  if ((tid & 63) == 0) { r1[tid >> 6] = s1; r2[tid >> 6] = s2; }
  __syncthreads();
  s1 = r1[0] + r1[1] + r1[2] + r1[3];
  s2 = r2[0] + r2[1] + r2[2] + r2[3];
  const float mu = s1 * (1.0f / 1024.0f);
  const float var = s2 * (1.0f / 1024.0f) - mu * mu;
  const float rs = rsqrtf(var + 1e-5f);
  float4 ov;
  ov.x = (y.x - mu) * rs; ov.y = (y.y - mu) * rs;
  ov.z = (y.z - mu) * rs; ov.w = (y.w - mu) * rs;
  ((float4*)o)[base] = ov;
}

__global__ __launch_bounds__(256) void ln_add_bf16(const float* __restrict__ a,
                                                   const float* __restrict__ b,
                                                   u16* __restrict__ o) {
  const int row = blockIdx.x;
  const int tid = threadIdx.x;
  const size_t base = (size_t)row * 256 + tid;
  const float4 av = ((const float4*)a)[base];
  const float4 bv = ((const float4*)b)[base];
  float4 y;
  y.x = av.x + bv.x; y.y = av.y + bv.y;
  y.z = av.z + bv.z; y.w = av.w + bv.w;
  float s1 = y.x + y.y + y.z + y.w;
  float s2 = y.x * y.x + y.y * y.y + y.z * y.z + y.w * y.w;
#pragma unroll
  for (int off = 32; off > 0; off >>= 1) {
    s1 += __shfl_xor(s1, off);
    s2 += __shfl_xor(s2, off);
  }
  __shared__ float r1[4];
  __shared__ float r2[4];
  if ((tid & 63) == 0) { r1[tid >> 6] = s1; r2[tid >> 6] = s2; }
  __syncthreads();
  s1 = r1[0] + r1[1] + r1[2] + r1[3];
  s2 = r2[0] + r2[1] + r2[2] + r2[3];
  const float mu = s1 * (1.0f / 1024.0f);
  const float var = s2 * (1.0f / 1024.0f) - mu * mu;
  const float rs = rsqrtf(var + 1e-5f);
  ushort4 ov;
  ov.x = f2bf((y.x - mu) * rs); ov.y = f2bf((y.y - mu) * rs);
  ov.z = f2bf((y.z - mu) * rs); ov.w = f2bf((y.w - mu) * rs);
  ((ushort4*)o)[base] = ov;
}

// ---------------------------------------------------------------------------
extern "C" void kernel_launch(void* const* d_in, const int* in_sizes, int n_in,
                              void* d_out, int out_size, void* d_ws, size_t ws_size,
                              hipStream_t stream) {
  const float* x  = (const float*)d_in[0];
  const float* Wq = (const float*)d_in[1];
  const float* Wk = (const float*)d_in[2];
  const float* Wv = (const float*)d_in[3];
  const float* Wl = (const float*)d_in[4];
  float* out = (float*)d_out;

  char* w8 = (char*)d_ws;
  u16* xh  = (u16*)(w8 + (0ull << 20));
  u16* xl  = (u16*)(w8 + (16ull << 20));
  u16* khT = (u16*)(w8 + (16ull << 20));
  u16* klT = (u16*)(w8 + (18ull << 20));
  u16* qh  = (u16*)(w8 + (32ull << 20));
  u16* ql  = (u16*)(w8 + (34ull << 20));
  u16* krh = (u16*)(w8 + (36ull << 20));
  u16* krl = (u16*)(w8 + (38ull << 20));
  u16* hb  = (u16*)(w8 + (32ull << 20));
  u16* vtt = (u16*)(w8 + (48ull << 20));
  float* sa = (float*)(w8 + (64ull << 20));
  u16* wqh = (u16*)(w8 + (92ull << 20));
  u16* wql = (u16*)(w8 + (92ull << 20) + (256ull << 10));
  u16* wkh = (u16*)(w8 + (92ull << 20) + (512ull << 10));
  u16* wkl = (u16*)(w8 + (92ull << 20) + (768ull << 10));
  u16* Wvb = (u16*)(w8 + (96ull << 20));
  u16* Wlb = (u16*)(w8 + (98ull << 20));

  split_hl<<<8192, 256, 0, stream>>>(x, xh, xl);
  cvt_bf16<<<512, 256, 0, stream>>>(Wv, Wvb);
  cvt_bf16<<<512, 256, 0, stream>>>(Wl, Wlb);
  // v-GEMM writes the fragment-tiled vtt DIRECTLY (mode 2); repack fused.
  gemm_mfma<2><<<dim3(64, 8), 256, 0, stream>>>(Wvb, xh, (void*)vtt, D_IN, N_TOK, D_IN);
  split_hl<<<128, 256, 0, stream>>>(Wq, wqh, wql);
  split_hl<<<128, 256, 0, stream>>>(Wk, wkh, wkl);
  gemm_hilo<<<dim3(2, 128), 256, 0, stream>>>(xh, xl, wqh, wql, qh, ql,
                                              wkh, wkl, krh, krl, D_IN);
  repack_k<<<512, 256, 0, stream>>>(krh, krl, khT, klT);
  flash_attn_mfma<<<dim3(2, 128), 512, 0, stream>>>(qh, ql, khT, klT, vtt, sa);
  ln_add_bf16<<<N_TOK, 256, 0, stream>>>(x, sa, hb);
  gemm_mfma<1><<<dim3(8, 64), 256, 0, stream>>>(hb, Wlb, (void*)out, N_TOK, D_IN, D_IN);
  ln_add<<<N_TOK, 256, 0, stream>>>(sa, out, out);
}